// Round 2
// baseline (1058.340 us; speedup 1.0000x reference)
//
#include <hip/hip_runtime.h>
#include <hip/hip_bf16.h>
#include <math.h>

// MoE: B=4 S=2048 D=1024 E=8 K=2 H=4096
// R2: + LDS slot swizzle (8-way -> 2-way bank conflicts), launch_bounds(256,4)
//     for 4 blocks/CU, nt-major block order (B column-strip L2 locality),
//     ushort4 transpose writes.

#define TOK     8192
#define DMODEL  1024
#define NEXP    8
#define HFF     4096
#define NASSIGN 16384
#define SLOTPAD 16512   // NASSIGN + 128 pad rows (partial-tile overreads)
#define BM      128
#define BN      128
#define BK      32
#define MAXRT   135     // sum_e ceil(n_e/128) <= 16384/128 + 7

typedef __attribute__((ext_vector_type(8))) short s16x8;
typedef __attribute__((ext_vector_type(4))) float f32x4;

__device__ __forceinline__ void gll16(const void* g, void* l) {
  __builtin_amdgcn_global_load_lds((const __attribute__((address_space(1))) void*)g,
                                   (__attribute__((address_space(3))) void*)l, 16, 0, 0);
}

// ---------- transpose + f32->bf16 convert: in [R][C] f32 -> out [C][R] bf16, per expert (z) ----------
__global__ void transpose_cvt(const float* __restrict__ in, __hip_bfloat16* __restrict__ out,
                              int R, int C) {
  __shared__ float t[64][65];
  const float* src = in + (size_t)blockIdx.z * R * C;
  __hip_bfloat16* dst = out + (size_t)blockIdx.z * R * C;
  const int r0 = blockIdx.y * 64, c0 = blockIdx.x * 64;
  const int tc = threadIdx.x & 63, tr = threadIdx.x >> 6;  // tr in 0..3
#pragma unroll
  for (int i = 0; i < 16; ++i) {
    int r = i * 4 + tr;
    t[r][tc] = src[(size_t)(r0 + r) * C + c0 + tc];
  }
  __syncthreads();
  // write phase: each lane writes 4 consecutive R-elements (ushort4, 8 B/lane)
  const int jl = (threadIdx.x & 15) * 4;   // row offset within tile
  const int cw = threadIdx.x >> 4;         // 0..15: col within pass
#pragma unroll
  for (int p = 0; p < 4; ++p) {
    const int cc = p * 16 + cw;
    union { ushort4 u; __hip_bfloat16 h[4]; } o;
#pragma unroll
    for (int u = 0; u < 4; ++u) o.h[u] = __float2bfloat16(t[jl + u][cc]);
    *(ushort4*)(dst + (size_t)(c0 + cc) * R + r0 + jl) = o.u;
  }
}

// ---------- router: fp32 logits -> softmax -> top-2 (first-index tie-break) ----------
__global__ void router_kernel(const float* __restrict__ x, const float* __restrict__ Wg,
                              const float* __restrict__ bg, int* __restrict__ idx,
                              float* __restrict__ wtok, int* __restrict__ counts) {
  __shared__ int scnt[NEXP];
  if (threadIdx.x < NEXP) scnt[threadIdx.x] = 0;
  __syncthreads();
  const int wave = threadIdx.x >> 6, lane = threadIdx.x & 63;
  const int t = blockIdx.x * 4 + wave;
  float acc[NEXP];
#pragma unroll
  for (int e = 0; e < NEXP; ++e) acc[e] = 0.f;
  const float* xr = x + (size_t)t * DMODEL + lane * 16;
#pragma unroll
  for (int j = 0; j < 4; ++j) {
    float4 xv = *(const float4*)(xr + j * 4);
    const float* wr = Wg + (size_t)(lane * 16 + j * 4) * NEXP;
#pragma unroll
    for (int u = 0; u < 4; ++u) {
      float xs = (&xv.x)[u];
      float4 w0 = *(const float4*)(wr + u * NEXP);
      float4 w1 = *(const float4*)(wr + u * NEXP + 4);
      acc[0] += xs * w0.x; acc[1] += xs * w0.y; acc[2] += xs * w0.z; acc[3] += xs * w0.w;
      acc[4] += xs * w1.x; acc[5] += xs * w1.y; acc[6] += xs * w1.z; acc[7] += xs * w1.w;
    }
  }
#pragma unroll
  for (int off = 32; off >= 1; off >>= 1) {
#pragma unroll
    for (int e = 0; e < NEXP; ++e) acc[e] += __shfl_xor(acc[e], off, 64);
  }
  if (lane == 0) {
    float l[NEXP], m = -1e30f;
#pragma unroll
    for (int e = 0; e < NEXP; ++e) { l[e] = acc[e] + bg[e]; m = fmaxf(m, l[e]); }
    float p[NEXP], s = 0.f;
#pragma unroll
    for (int e = 0; e < NEXP; ++e) { p[e] = expf(l[e] - m); s += p[e]; }
    float inv = 1.f / s;
#pragma unroll
    for (int e = 0; e < NEXP; ++e) p[e] *= inv;
    int i0 = 0; float v0 = p[0];
#pragma unroll
    for (int e = 1; e < NEXP; ++e) if (p[e] > v0) { v0 = p[e]; i0 = e; }
    int i1 = -1; float v1 = -1e30f;
#pragma unroll
    for (int e = 0; e < NEXP; ++e) if (e != i0 && p[e] > v1) { v1 = p[e]; i1 = e; }
    idx[2 * t] = i0; idx[2 * t + 1] = i1;
    wtok[2 * t] = v0; wtok[2 * t + 1] = v1;
    atomicAdd(&scnt[i0], 1); atomicAdd(&scnt[i1], 1);
  }
  __syncthreads();
  if (threadIdx.x < NEXP) atomicAdd(&counts[threadIdx.x], scnt[threadIdx.x]);
}

// ctrl layout (ints): [0..7]=counts [8..15]=cursor [16..24]=expOff [26..34]=tileRowOff
__global__ void scan_kernel(int* ctrl) {
  if (threadIdx.x == 0 && blockIdx.x == 0) {
    int* counts = ctrl;
    int* cursor = ctrl + 8;
    int* expOff = ctrl + 16;
    int* tro = ctrl + 26;
    expOff[0] = 0; tro[0] = 0;
    for (int e = 0; e < NEXP; ++e) {
      expOff[e + 1] = expOff[e] + counts[e];
      tro[e + 1] = tro[e] + (counts[e] + BM - 1) / BM;
      cursor[e] = expOff[e];
    }
  }
}

__global__ void scatter_kernel(const int* __restrict__ idx, const float* __restrict__ wtok,
                               int* ctrl, int* __restrict__ perm, float* __restrict__ wslot,
                               int* __restrict__ inv) {
  __shared__ int lcnt[NEXP];
  __shared__ int lbase[NEXP];
  const int t = blockIdx.x * 256 + threadIdx.x;
  if (threadIdx.x < NEXP) lcnt[threadIdx.x] = 0;
  __syncthreads();
  const int e0 = idx[2 * t], e1 = idx[2 * t + 1];
  const int l0 = atomicAdd(&lcnt[e0], 1);
  const int l1 = atomicAdd(&lcnt[e1], 1);
  __syncthreads();
  if (threadIdx.x < NEXP)
    lbase[threadIdx.x] = atomicAdd(&ctrl[8 + threadIdx.x], lcnt[threadIdx.x]);
  __syncthreads();
  const int s0 = lbase[e0] + l0, s1 = lbase[e1] + l1;
  perm[s0] = t; perm[s1] = t;
  wslot[s0] = wtok[2 * t]; wslot[s1] = wtok[2 * t + 1];
  inv[2 * t] = s0; inv[2 * t + 1] = s1;
}

__global__ void gather_cvt_x(const float* __restrict__ x, const int* __restrict__ perm,
                             __hip_bfloat16* __restrict__ xg) {
  const int slot = blockIdx.x;
  const int t = perm[slot];
  const float4 v = *(const float4*)(x + (size_t)t * DMODEL + threadIdx.x * 4);
  union { ushort4 u; __hip_bfloat16 h[4]; } o;
  o.h[0] = __float2bfloat16(v.x); o.h[1] = __float2bfloat16(v.y);
  o.h[2] = __float2bfloat16(v.z); o.h[3] = __float2bfloat16(v.w);
  *(ushort4*)(xg + (size_t)slot * DMODEL + threadIdx.x * 4) = o.u;
}

// ---- shared GEMM tile body (bank-conflict-swizzled LDS layout) ----
// LDS slot s in [0,512): holds row r=s>>2, global k-chunk kc with
// slot-within-row sl = (kc + (r>>1)) & 3  =>  kc = (sl - ((r>>1)&3)) & 3.
// Fragment read row r, quad q -> slot r*4 + ((q + (r>>1)) & 3): 2-way banks.

// ---------- grouped GEMM1: h = gelu(xg @ W1t^T + b1) ----------
__global__ __launch_bounds__(256, 4) void gemm1_kernel(
    const __hip_bfloat16* __restrict__ xg, const __hip_bfloat16* __restrict__ w1t,
    const float* __restrict__ b1, __hip_bfloat16* __restrict__ hbuf,
    const int* __restrict__ ctrl) {
  const int* expOff = ctrl + 16;
  const int* tro = ctrl + 26;
  const int w = blockIdx.x;
  const int rt = w % MAXRT, nt = w / MAXRT;   // nt-major: consecutive blocks share B strip
  if (rt >= tro[NEXP]) return;
  int e = 0;
#pragma unroll
  for (int q = 1; q < NEXP; ++q) if (tro[q] <= rt) e = q;
  const int rowBase = expOff[e] + (rt - tro[e]) * BM;
  const int rowEnd = expOff[e + 1];

  __shared__ __hip_bfloat16 lA[BM * BK];
  __shared__ __hip_bfloat16 lB[BN * BK];

  const int tid = threadIdx.x;
  const int lane = tid & 63, wave = tid >> 6;
  const int quad = lane >> 4, lm = lane & 15;
  const int waveM = (wave >> 1) * 64, waveN = (wave & 1) * 64;

  f32x4 acc[4][4];
#pragma unroll
  for (int a = 0; a < 4; ++a)
#pragma unroll
    for (int b = 0; b < 4; ++b) acc[a][b] = (f32x4){0.f, 0.f, 0.f, 0.f};

  // staging addresses (swizzled k-chunk)
  const int c0 = tid, c1 = tid + 256;
  const int rA0 = c0 >> 2, rA1 = c1 >> 2;
  const int k0 = ((c0 & 3) - ((rA0 >> 1) & 3) + 4) & 3;
  const int k1 = ((c1 & 3) - ((rA1 >> 1) & 3) + 4) & 3;
  const __hip_bfloat16* gA0 = xg + (size_t)(rowBase + rA0) * DMODEL + k0 * 8;
  const __hip_bfloat16* gA1 = xg + (size_t)(rowBase + rA1) * DMODEL + k1 * 8;
  const __hip_bfloat16* bbase = w1t + (size_t)e * HFF * DMODEL + (size_t)nt * BN * DMODEL;
  const __hip_bfloat16* gB0 = bbase + (size_t)rA0 * DMODEL + k0 * 8;
  const __hip_bfloat16* gB1 = bbase + (size_t)rA1 * DMODEL + k1 * 8;
  __hip_bfloat16* sA0 = lA + c0 * 8; __hip_bfloat16* sA1 = lA + c1 * 8;
  __hip_bfloat16* sB0 = lB + c0 * 8; __hip_bfloat16* sB1 = lB + c1 * 8;

  // fragment LDS offsets (elements), loop-invariant
  int aOff[4], bOff[4];
#pragma unroll
  for (int tm = 0; tm < 4; ++tm) {
    int r = waveM + tm * 16 + lm;
    aOff[tm] = (r * 4 + ((quad + (r >> 1)) & 3)) * 8;
  }
#pragma unroll
  for (int tn = 0; tn < 4; ++tn) {
    int r = waveN + tn * 16 + lm;
    bOff[tn] = (r * 4 + ((quad + (r >> 1)) & 3)) * 8;
  }

  for (int kt = 0; kt < DMODEL / BK; ++kt) {
    gll16(gA0, sA0); gll16(gA1, sA1);
    gll16(gB0, sB0); gll16(gB1, sB1);
    gA0 += BK; gA1 += BK; gB0 += BK; gB1 += BK;
    __syncthreads();
    s16x8 af[4], bfr[4];
#pragma unroll
    for (int tm = 0; tm < 4; ++tm) af[tm] = *(const s16x8*)(lA + aOff[tm]);
#pragma unroll
    for (int tn = 0; tn < 4; ++tn) bfr[tn] = *(const s16x8*)(lB + bOff[tn]);
#pragma unroll
    for (int tm = 0; tm < 4; ++tm)
#pragma unroll
      for (int tn = 0; tn < 4; ++tn)
        acc[tm][tn] = __builtin_amdgcn_mfma_f32_16x16x32_bf16(af[tm], bfr[tn], acc[tm][tn], 0, 0, 0);
    __syncthreads();
  }

  const int colBase = nt * BN + waveN;
  float bv[4];
#pragma unroll
  for (int tn = 0; tn < 4; ++tn) bv[tn] = b1[e * HFF + colBase + tn * 16 + lm];
#pragma unroll
  for (int tm = 0; tm < 4; ++tm) {
    const int rb = rowBase + waveM + tm * 16 + quad * 4;
#pragma unroll
    for (int reg = 0; reg < 4; ++reg) {
      const int row = rb + reg;
      if (row < rowEnd) {
#pragma unroll
        for (int tn = 0; tn < 4; ++tn) {
          float v = acc[tm][tn][reg] + bv[tn];
          v = 0.5f * v * (1.f + erff(v * 0.70710678118654752f));  // exact gelu
          hbuf[(size_t)row * HFF + colBase + tn * 16 + lm] = __float2bfloat16(v);
        }
      }
    }
  }
}

// ---------- grouped GEMM2: y = (h @ W2t^T + b2) * w_gate, fp32 out ----------
__global__ __launch_bounds__(256, 4) void gemm2_kernel(
    const __hip_bfloat16* __restrict__ hbuf, const __hip_bfloat16* __restrict__ w2t,
    const float* __restrict__ b2, const float* __restrict__ wslot,
    float* __restrict__ y, const int* __restrict__ ctrl) {
  const int* expOff = ctrl + 16;
  const int* tro = ctrl + 26;
  const int w = blockIdx.x;
  const int rt = w % MAXRT, nt = w / MAXRT;
  if (rt >= tro[NEXP]) return;
  int e = 0;
#pragma unroll
  for (int q = 1; q < NEXP; ++q) if (tro[q] <= rt) e = q;
  const int rowBase = expOff[e] + (rt - tro[e]) * BM;
  const int rowEnd = expOff[e + 1];

  __shared__ __hip_bfloat16 lA[BM * BK];
  __shared__ __hip_bfloat16 lB[BN * BK];

  const int tid = threadIdx.x;
  const int lane = tid & 63, wave = tid >> 6;
  const int quad = lane >> 4, lm = lane & 15;
  const int waveM = (wave >> 1) * 64, waveN = (wave & 1) * 64;

  f32x4 acc[4][4];
#pragma unroll
  for (int a = 0; a < 4; ++a)
#pragma unroll
    for (int b = 0; b < 4; ++b) acc[a][b] = (f32x4){0.f, 0.f, 0.f, 0.f};

  const int c0 = tid, c1 = tid + 256;
  const int rA0 = c0 >> 2, rA1 = c1 >> 2;
  const int k0 = ((c0 & 3) - ((rA0 >> 1) & 3) + 4) & 3;
  const int k1 = ((c1 & 3) - ((rA1 >> 1) & 3) + 4) & 3;
  const __hip_bfloat16* gA0 = hbuf + (size_t)(rowBase + rA0) * HFF + k0 * 8;
  const __hip_bfloat16* gA1 = hbuf + (size_t)(rowBase + rA1) * HFF + k1 * 8;
  const __hip_bfloat16* bbase = w2t + (size_t)e * DMODEL * HFF + (size_t)nt * BN * HFF;
  const __hip_bfloat16* gB0 = bbase + (size_t)rA0 * HFF + k0 * 8;
  const __hip_bfloat16* gB1 = bbase + (size_t)rA1 * HFF + k1 * 8;
  __hip_bfloat16* sA0 = lA + c0 * 8; __hip_bfloat16* sA1 = lA + c1 * 8;
  __hip_bfloat16* sB0 = lB + c0 * 8; __hip_bfloat16* sB1 = lB + c1 * 8;

  int aOff[4], bOff[4];
#pragma unroll
  for (int tm = 0; tm < 4; ++tm) {
    int r = waveM + tm * 16 + lm;
    aOff[tm] = (r * 4 + ((quad + (r >> 1)) & 3)) * 8;
  }
#pragma unroll
  for (int tn = 0; tn < 4; ++tn) {
    int r = waveN + tn * 16 + lm;
    bOff[tn] = (r * 4 + ((quad + (r >> 1)) & 3)) * 8;
  }

  for (int kt = 0; kt < HFF / BK; ++kt) {
    gll16(gA0, sA0); gll16(gA1, sA1);
    gll16(gB0, sB0); gll16(gB1, sB1);
    gA0 += BK; gA1 += BK; gB0 += BK; gB1 += BK;
    __syncthreads();
    s16x8 af[4], bfr[4];
#pragma unroll
    for (int tm = 0; tm < 4; ++tm) af[tm] = *(const s16x8*)(lA + aOff[tm]);
#pragma unroll
    for (int tn = 0; tn < 4; ++tn) bfr[tn] = *(const s16x8*)(lB + bOff[tn]);
#pragma unroll
    for (int tm = 0; tm < 4; ++tm)
#pragma unroll
      for (int tn = 0; tn < 4; ++tn)
        acc[tm][tn] = __builtin_amdgcn_mfma_f32_16x16x32_bf16(af[tm], bfr[tn], acc[tm][tn], 0, 0, 0);
    __syncthreads();
  }

  const int colBase = nt * BN + waveN;
  float bv[4];
#pragma unroll
  for (int tn = 0; tn < 4; ++tn) bv[tn] = b2[e * DMODEL + colBase + tn * 16 + lm];
#pragma unroll
  for (int tm = 0; tm < 4; ++tm) {
    const int rb = rowBase + waveM + tm * 16 + quad * 4;
#pragma unroll
    for (int reg = 0; reg < 4; ++reg) {
      const int row = rb + reg;
      if (row < rowEnd) {
        const float wr = wslot[row];
#pragma unroll
        for (int tn = 0; tn < 4; ++tn)
          y[(size_t)row * DMODEL + colBase + tn * 16 + lm] = (acc[tm][tn][reg] + bv[tn]) * wr;
      }
    }
  }
}

__global__ void combine_kernel(const float* __restrict__ y, const int* __restrict__ inv,
                               float* __restrict__ out) {
  const int t = blockIdx.x;
  const int s0 = inv[2 * t], s1 = inv[2 * t + 1];
  const int i = threadIdx.x * 4;
  float4 a = *(const float4*)(y + (size_t)s0 * DMODEL + i);
  float4 b = *(const float4*)(y + (size_t)s1 * DMODEL + i);
  float4 o;
  o.x = a.x + b.x; o.y = a.y + b.y; o.z = a.z + b.z; o.w = a.w + b.w;
  *(float4*)(out + (size_t)t * DMODEL + i) = o;
}

extern "C" void kernel_launch(void* const* d_in, const int* in_sizes, int n_in,
                              void* d_out, int out_size, void* d_ws, size_t ws_size,
                              hipStream_t stream) {
  const float* x  = (const float*)d_in[0];
  const float* Wg = (const float*)d_in[1];
  const float* bg = (const float*)d_in[2];
  const float* W1 = (const float*)d_in[3];
  const float* b1 = (const float*)d_in[4];
  const float* W2 = (const float*)d_in[5];
  const float* b2 = (const float*)d_in[6];
  float* out = (float*)d_out;

  char* ws = (char*)d_ws;
  size_t off = 0;
  auto take = [&](size_t bytes) -> char* {
    char* p = ws + off;
    off = (off + bytes + 255) & ~(size_t)255;
    return p;
  };
  int*   ctrl  = (int*)take(64 * sizeof(int));
  int*   idx   = (int*)take((size_t)TOK * 2 * 4);
  float* wtok  = (float*)take((size_t)TOK * 2 * 4);
  int*   perm  = (int*)take((size_t)SLOTPAD * 4);
  float* wslot = (float*)take((size_t)SLOTPAD * 4);
  int*   inv   = (int*)take((size_t)TOK * 2 * 4);
  __hip_bfloat16* W1t = (__hip_bfloat16*)take((size_t)NEXP * HFF * DMODEL * 2);
  __hip_bfloat16* W2t = (__hip_bfloat16*)take((size_t)NEXP * DMODEL * HFF * 2);
  __hip_bfloat16* xgb = (__hip_bfloat16*)take((size_t)SLOTPAD * DMODEL * 2);
  __hip_bfloat16* hb  = (__hip_bfloat16*)take((size_t)SLOTPAD * HFF * 2);
  float*          yb  = (float*)take((size_t)SLOTPAD * DMODEL * 4);
  (void)ws_size; (void)in_sizes; (void)n_in; (void)out_size;

  hipMemsetAsync(ctrl, 0, 64 * sizeof(int), stream);
  transpose_cvt<<<dim3(HFF / 64, DMODEL / 64, NEXP), 256, 0, stream>>>(W1, W1t, DMODEL, HFF);
  transpose_cvt<<<dim3(DMODEL / 64, HFF / 64, NEXP), 256, 0, stream>>>(W2, W2t, HFF, DMODEL);
  router_kernel<<<TOK / 4, 256, 0, stream>>>(x, Wg, bg, idx, wtok, ctrl);
  scan_kernel<<<1, 64, 0, stream>>>(ctrl);
  scatter_kernel<<<TOK / 256, 256, 0, stream>>>(idx, wtok, ctrl, perm, wslot, inv);
  gather_cvt_x<<<NASSIGN, 256, 0, stream>>>(x, perm, xgb);
  gemm1_kernel<<<MAXRT * (HFF / BN), 256, 0, stream>>>(xgb, W1t, b1, hb, ctrl);
  gemm2_kernel<<<MAXRT * (DMODEL / BN), 256, 0, stream>>>(hb, W2t, b2, wslot, yb, ctrl);
  combine_kernel<<<TOK, 256, 0, stream>>>(yb, inv, out);
}

// Round 3
// 794.528 us; speedup vs baseline: 1.3320x; 1.3320x over previous
//
#include <hip/hip_runtime.h>
#include <hip/hip_bf16.h>
#include <math.h>

// MoE: B=4 S=2048 D=1024 E=8 K=2 H=4096
// R3: revert to rt-major block order (R2's nt-major doubled FETCH: A re-streamed
//     per nt). BK=64 (8 global_load_lds in flight per drain, halves barriers),
//     XOR LDS swizzle (conflict-free), gemm2 fused with combine via atomicAdd.

#define TOK     8192
#define DMODEL  1024
#define NEXP    8
#define HFF     4096
#define NASSIGN 16384
#define SLOTPAD 16512   // NASSIGN + 128 pad rows (partial-tile overreads)
#define BM      128
#define BN      128
#define BK      64
#define MAXRT   135     // sum_e ceil(n_e/128) <= 16384/128 + 7

typedef __attribute__((ext_vector_type(8))) short s16x8;
typedef __attribute__((ext_vector_type(4))) float f32x4;

__device__ __forceinline__ void gll16(const void* g, void* l) {
  __builtin_amdgcn_global_load_lds((const __attribute__((address_space(1))) void*)g,
                                   (__attribute__((address_space(3))) void*)l, 16, 0, 0);
}

// ---------- transpose + f32->bf16 convert: in [R][C] f32 -> out [C][R] bf16, per expert (z) ----------
__global__ void transpose_cvt(const float* __restrict__ in, __hip_bfloat16* __restrict__ out,
                              int R, int C) {
  __shared__ float t[64][65];
  const float* src = in + (size_t)blockIdx.z * R * C;
  __hip_bfloat16* dst = out + (size_t)blockIdx.z * R * C;
  const int r0 = blockIdx.y * 64, c0 = blockIdx.x * 64;
  const int tc = threadIdx.x & 63, tr = threadIdx.x >> 6;  // tr in 0..3
#pragma unroll
  for (int i = 0; i < 16; ++i) {
    int r = i * 4 + tr;
    t[r][tc] = src[(size_t)(r0 + r) * C + c0 + tc];
  }
  __syncthreads();
  // write phase: each lane writes 4 consecutive R-elements (ushort4, 8 B/lane)
  const int jl = (threadIdx.x & 15) * 4;   // row offset within tile
  const int cw = threadIdx.x >> 4;         // 0..15: col within pass
#pragma unroll
  for (int p = 0; p < 4; ++p) {
    const int cc = p * 16 + cw;
    union { ushort4 u; __hip_bfloat16 h[4]; } o;
#pragma unroll
    for (int u = 0; u < 4; ++u) o.h[u] = __float2bfloat16(t[jl + u][cc]);
    *(ushort4*)(dst + (size_t)(c0 + cc) * R + r0 + jl) = o.u;
  }
}

// ---------- router: fp32 logits -> softmax -> top-2 (first-index tie-break) ----------
__global__ void router_kernel(const float* __restrict__ x, const float* __restrict__ Wg,
                              const float* __restrict__ bg, int* __restrict__ idx,
                              float* __restrict__ wtok, int* __restrict__ counts) {
  __shared__ int scnt[NEXP];
  if (threadIdx.x < NEXP) scnt[threadIdx.x] = 0;
  __syncthreads();
  const int wave = threadIdx.x >> 6, lane = threadIdx.x & 63;
  const int t = blockIdx.x * 4 + wave;
  float acc[NEXP];
#pragma unroll
  for (int e = 0; e < NEXP; ++e) acc[e] = 0.f;
  const float* xr = x + (size_t)t * DMODEL + lane * 16;
#pragma unroll
  for (int j = 0; j < 4; ++j) {
    float4 xv = *(const float4*)(xr + j * 4);
    const float* wr = Wg + (size_t)(lane * 16 + j * 4) * NEXP;
#pragma unroll
    for (int u = 0; u < 4; ++u) {
      float xs = (&xv.x)[u];
      float4 w0 = *(const float4*)(wr + u * NEXP);
      float4 w1 = *(const float4*)(wr + u * NEXP + 4);
      acc[0] += xs * w0.x; acc[1] += xs * w0.y; acc[2] += xs * w0.z; acc[3] += xs * w0.w;
      acc[4] += xs * w1.x; acc[5] += xs * w1.y; acc[6] += xs * w1.z; acc[7] += xs * w1.w;
    }
  }
#pragma unroll
  for (int off = 32; off >= 1; off >>= 1) {
#pragma unroll
    for (int e = 0; e < NEXP; ++e) acc[e] += __shfl_xor(acc[e], off, 64);
  }
  if (lane == 0) {
    float l[NEXP], m = -1e30f;
#pragma unroll
    for (int e = 0; e < NEXP; ++e) { l[e] = acc[e] + bg[e]; m = fmaxf(m, l[e]); }
    float p[NEXP], s = 0.f;
#pragma unroll
    for (int e = 0; e < NEXP; ++e) { p[e] = expf(l[e] - m); s += p[e]; }
    float inv = 1.f / s;
#pragma unroll
    for (int e = 0; e < NEXP; ++e) p[e] *= inv;
    int i0 = 0; float v0 = p[0];
#pragma unroll
    for (int e = 1; e < NEXP; ++e) if (p[e] > v0) { v0 = p[e]; i0 = e; }
    int i1 = -1; float v1 = -1e30f;
#pragma unroll
    for (int e = 0; e < NEXP; ++e) if (e != i0 && p[e] > v1) { v1 = p[e]; i1 = e; }
    idx[2 * t] = i0; idx[2 * t + 1] = i1;
    wtok[2 * t] = v0; wtok[2 * t + 1] = v1;
    atomicAdd(&scnt[i0], 1); atomicAdd(&scnt[i1], 1);
  }
  __syncthreads();
  if (threadIdx.x < NEXP) atomicAdd(&counts[threadIdx.x], scnt[threadIdx.x]);
}

// ctrl layout (ints): [0..7]=counts [8..15]=cursor [16..24]=expOff [26..34]=tileRowOff
__global__ void scan_kernel(int* ctrl) {
  if (threadIdx.x == 0 && blockIdx.x == 0) {
    int* counts = ctrl;
    int* cursor = ctrl + 8;
    int* expOff = ctrl + 16;
    int* tro = ctrl + 26;
    expOff[0] = 0; tro[0] = 0;
    for (int e = 0; e < NEXP; ++e) {
      expOff[e + 1] = expOff[e] + counts[e];
      tro[e + 1] = tro[e] + (counts[e] + BM - 1) / BM;
      cursor[e] = expOff[e];
    }
  }
}

__global__ void scatter_kernel(const int* __restrict__ idx, const float* __restrict__ wtok,
                               int* ctrl, int* __restrict__ perm, float* __restrict__ wslot) {
  __shared__ int lcnt[NEXP];
  __shared__ int lbase[NEXP];
  const int t = blockIdx.x * 256 + threadIdx.x;
  if (threadIdx.x < NEXP) lcnt[threadIdx.x] = 0;
  __syncthreads();
  const int e0 = idx[2 * t], e1 = idx[2 * t + 1];
  const int l0 = atomicAdd(&lcnt[e0], 1);
  const int l1 = atomicAdd(&lcnt[e1], 1);
  __syncthreads();
  if (threadIdx.x < NEXP)
    lbase[threadIdx.x] = atomicAdd(&ctrl[8 + threadIdx.x], lcnt[threadIdx.x]);
  __syncthreads();
  const int s0 = lbase[e0] + l0, s1 = lbase[e1] + l1;
  perm[s0] = t; perm[s1] = t;
  wslot[s0] = wtok[2 * t]; wslot[s1] = wtok[2 * t + 1];
}

__global__ void gather_cvt_x(const float* __restrict__ x, const int* __restrict__ perm,
                             __hip_bfloat16* __restrict__ xg) {
  const int slot = blockIdx.x;
  const int t = perm[slot];
  const float4 v = *(const float4*)(x + (size_t)t * DMODEL + threadIdx.x * 4);
  union { ushort4 u; __hip_bfloat16 h[4]; } o;
  o.h[0] = __float2bfloat16(v.x); o.h[1] = __float2bfloat16(v.y);
  o.h[2] = __float2bfloat16(v.z); o.h[3] = __float2bfloat16(v.w);
  *(ushort4*)(xg + (size_t)slot * DMODEL + threadIdx.x * 4) = o.u;
}

// ---- LDS layout (BK=64): per matrix 128 rows x 8 chunks of 8 bf16 (16 B).
// chunk kc of row r stored at slot sl = kc ^ (r&7). Staging slot s = tid+256*i:
// r=s>>3, sl=s&7, kc=sl^(r&7) -> wave-lane-contiguous LDS dests (gll16-legal).
// Fragment read (k-half h, quad q): kc=h*4+q -> sl = (q ^ (r&7)) ^ (4h);
// byte addr flips bit6 between halves; 2 lanes/bank-group = conflict-free.

// ---------- grouped GEMM1: h = gelu(xg @ W1t^T + b1) ----------
__global__ __launch_bounds__(256, 3) void gemm1_kernel(
    const __hip_bfloat16* __restrict__ xg, const __hip_bfloat16* __restrict__ w1t,
    const float* __restrict__ b1, __hip_bfloat16* __restrict__ hbuf,
    const int* __restrict__ ctrl) {
  const int* expOff = ctrl + 16;
  const int* tro = ctrl + 26;
  const int w = blockIdx.x;
  const int rt = w >> 5, nt = w & 31;   // rt-major; XCD = w%8 tracks nt%8 (B-strip locality)
  if (rt >= tro[NEXP]) return;
  int e = 0;
#pragma unroll
  for (int q = 1; q < NEXP; ++q) if (tro[q] <= rt) e = q;
  const int rowBase = expOff[e] + (rt - tro[e]) * BM;
  const int rowEnd = expOff[e + 1];

  __shared__ __hip_bfloat16 lA[BM * BK];
  __shared__ __hip_bfloat16 lB[BN * BK];

  const int tid = threadIdx.x;
  const int lane = tid & 63, wave = tid >> 6;
  const int quad = lane >> 4, lm = lane & 15;
  const int waveM = (wave >> 1) * 64, waveN = (wave & 1) * 64;

  f32x4 acc[4][4];
#pragma unroll
  for (int a = 0; a < 4; ++a)
#pragma unroll
    for (int b = 0; b < 4; ++b) acc[a][b] = (f32x4){0.f, 0.f, 0.f, 0.f};

  const __hip_bfloat16* bbase = w1t + (size_t)e * HFF * DMODEL + (size_t)nt * BN * DMODEL;
  const __hip_bfloat16* gA[4]; const __hip_bfloat16* gB[4];
  __hip_bfloat16* sA[4]; __hip_bfloat16* sB[4];
#pragma unroll
  for (int i = 0; i < 4; ++i) {
    const int s = tid + 256 * i;
    const int r = s >> 3, sl = s & 7, kc = sl ^ (r & 7);
    gA[i] = xg + (size_t)(rowBase + r) * DMODEL + kc * 8;
    gB[i] = bbase + (size_t)r * DMODEL + kc * 8;
    sA[i] = lA + s * 8; sB[i] = lB + s * 8;
  }

  int aOff[4], bOff[4];   // h=0 element offsets; h=1 = ^32
#pragma unroll
  for (int tm = 0; tm < 4; ++tm) {
    int r = waveM + tm * 16 + lm;
    aOff[tm] = r * 64 + (quad ^ (r & 7)) * 8;
  }
#pragma unroll
  for (int tn = 0; tn < 4; ++tn) {
    int r = waveN + tn * 16 + lm;
    bOff[tn] = r * 64 + (quad ^ (r & 7)) * 8;
  }

  for (int kt = 0; kt < DMODEL / BK; ++kt) {
#pragma unroll
    for (int i = 0; i < 4; ++i) { gll16(gA[i], sA[i]); gll16(gB[i], sB[i]); }
#pragma unroll
    for (int i = 0; i < 4; ++i) { gA[i] += BK; gB[i] += BK; }
    __syncthreads();
#pragma unroll
    for (int h = 0; h < 2; ++h) {
      s16x8 af[4], bfr[4];
#pragma unroll
      for (int tm = 0; tm < 4; ++tm) af[tm] = *(const s16x8*)(lA + (aOff[tm] ^ (h * 32)));
#pragma unroll
      for (int tn = 0; tn < 4; ++tn) bfr[tn] = *(const s16x8*)(lB + (bOff[tn] ^ (h * 32)));
#pragma unroll
      for (int tm = 0; tm < 4; ++tm)
#pragma unroll
        for (int tn = 0; tn < 4; ++tn)
          acc[tm][tn] = __builtin_amdgcn_mfma_f32_16x16x32_bf16(af[tm], bfr[tn], acc[tm][tn], 0, 0, 0);
    }
    __syncthreads();
  }

  const int colBase = nt * BN + waveN;
  float bv[4];
#pragma unroll
  for (int tn = 0; tn < 4; ++tn) bv[tn] = b1[e * HFF + colBase + tn * 16 + lm];
#pragma unroll
  for (int tm = 0; tm < 4; ++tm) {
    const int rb = rowBase + waveM + tm * 16 + quad * 4;
#pragma unroll
    for (int reg = 0; reg < 4; ++reg) {
      const int row = rb + reg;
      if (row < rowEnd) {
#pragma unroll
        for (int tn = 0; tn < 4; ++tn) {
          float v = acc[tm][tn][reg] + bv[tn];
          v = 0.5f * v * (1.f + erff(v * 0.70710678118654752f));  // exact gelu
          hbuf[(size_t)row * HFF + colBase + tn * 16 + lm] = __float2bfloat16(v);
        }
      }
    }
  }
}

// ---------- grouped GEMM2 fused with combine: out[token] += (h @ W2t^T + b2) * w_gate ----------
__global__ __launch_bounds__(256, 3) void gemm2_kernel(
    const __hip_bfloat16* __restrict__ hbuf, const __hip_bfloat16* __restrict__ w2t,
    const float* __restrict__ b2, const float* __restrict__ wslot,
    const int* __restrict__ perm, float* __restrict__ out, const int* __restrict__ ctrl) {
  const int* expOff = ctrl + 16;
  const int* tro = ctrl + 26;
  const int w = blockIdx.x;
  const int rt = w >> 3, nt = w & 7;
  if (rt >= tro[NEXP]) return;
  int e = 0;
#pragma unroll
  for (int q = 1; q < NEXP; ++q) if (tro[q] <= rt) e = q;
  const int rowBase = expOff[e] + (rt - tro[e]) * BM;
  const int rowEnd = expOff[e + 1];

  __shared__ __hip_bfloat16 lA[BM * BK];
  __shared__ __hip_bfloat16 lB[BN * BK];

  const int tid = threadIdx.x;
  const int lane = tid & 63, wave = tid >> 6;
  const int quad = lane >> 4, lm = lane & 15;
  const int waveM = (wave >> 1) * 64, waveN = (wave & 1) * 64;

  f32x4 acc[4][4];
#pragma unroll
  for (int a = 0; a < 4; ++a)
#pragma unroll
    for (int b = 0; b < 4; ++b) acc[a][b] = (f32x4){0.f, 0.f, 0.f, 0.f};

  const __hip_bfloat16* bbase = w2t + (size_t)e * DMODEL * HFF + (size_t)nt * BN * HFF;
  const __hip_bfloat16* gA[4]; const __hip_bfloat16* gB[4];
  __hip_bfloat16* sA[4]; __hip_bfloat16* sB[4];
#pragma unroll
  for (int i = 0; i < 4; ++i) {
    const int s = tid + 256 * i;
    const int r = s >> 3, sl = s & 7, kc = sl ^ (r & 7);
    gA[i] = hbuf + (size_t)(rowBase + r) * HFF + kc * 8;
    gB[i] = bbase + (size_t)r * HFF + kc * 8;
    sA[i] = lA + s * 8; sB[i] = lB + s * 8;
  }

  int aOff[4], bOff[4];
#pragma unroll
  for (int tm = 0; tm < 4; ++tm) {
    int r = waveM + tm * 16 + lm;
    aOff[tm] = r * 64 + (quad ^ (r & 7)) * 8;
  }
#pragma unroll
  for (int tn = 0; tn < 4; ++tn) {
    int r = waveN + tn * 16 + lm;
    bOff[tn] = r * 64 + (quad ^ (r & 7)) * 8;
  }

  for (int kt = 0; kt < HFF / BK; ++kt) {
#pragma unroll
    for (int i = 0; i < 4; ++i) { gll16(gA[i], sA[i]); gll16(gB[i], sB[i]); }
#pragma unroll
    for (int i = 0; i < 4; ++i) { gA[i] += BK; gB[i] += BK; }
    __syncthreads();
#pragma unroll
    for (int h = 0; h < 2; ++h) {
      s16x8 af[4], bfr[4];
#pragma unroll
      for (int tm = 0; tm < 4; ++tm) af[tm] = *(const s16x8*)(lA + (aOff[tm] ^ (h * 32)));
#pragma unroll
      for (int tn = 0; tn < 4; ++tn) bfr[tn] = *(const s16x8*)(lB + (bOff[tn] ^ (h * 32)));
#pragma unroll
      for (int tm = 0; tm < 4; ++tm)
#pragma unroll
        for (int tn = 0; tn < 4; ++tn)
          acc[tm][tn] = __builtin_amdgcn_mfma_f32_16x16x32_bf16(af[tm], bfr[tn], acc[tm][tn], 0, 0, 0);
    }
    __syncthreads();
  }

  const int colBase = nt * BN + waveN;
  float bv[4];
#pragma unroll
  for (int tn = 0; tn < 4; ++tn) bv[tn] = b2[e * DMODEL + colBase + tn * 16 + lm];
#pragma unroll
  for (int tm = 0; tm < 4; ++tm) {
    const int rb = rowBase + waveM + tm * 16 + quad * 4;
#pragma unroll
    for (int reg = 0; reg < 4; ++reg) {
      const int row = rb + reg;
      if (row < rowEnd) {
        const float wr = wslot[row];
        float* orow = out + (size_t)perm[row] * DMODEL + colBase;
#pragma unroll
        for (int tn = 0; tn < 4; ++tn)
          atomicAdd(orow + tn * 16 + lm, (acc[tm][tn][reg] + bv[tn]) * wr);
      }
    }
  }
}

extern "C" void kernel_launch(void* const* d_in, const int* in_sizes, int n_in,
                              void* d_out, int out_size, void* d_ws, size_t ws_size,
                              hipStream_t stream) {
  const float* x  = (const float*)d_in[0];
  const float* Wg = (const float*)d_in[1];
  const float* bg = (const float*)d_in[2];
  const float* W1 = (const float*)d_in[3];
  const float* b1 = (const float*)d_in[4];
  const float* W2 = (const float*)d_in[5];
  const float* b2 = (const float*)d_in[6];
  float* out = (float*)d_out;

  char* ws = (char*)d_ws;
  size_t off = 0;
  auto take = [&](size_t bytes) -> char* {
    char* p = ws + off;
    off = (off + bytes + 255) & ~(size_t)255;
    return p;
  };
  int*   ctrl  = (int*)take(64 * sizeof(int));
  int*   idx   = (int*)take((size_t)TOK * 2 * 4);
  float* wtok  = (float*)take((size_t)TOK * 2 * 4);
  int*   perm  = (int*)take((size_t)SLOTPAD * 4);
  float* wslot = (float*)take((size_t)SLOTPAD * 4);
  __hip_bfloat16* W1t = (__hip_bfloat16*)take((size_t)NEXP * HFF * DMODEL * 2);
  __hip_bfloat16* W2t = (__hip_bfloat16*)take((size_t)NEXP * DMODEL * HFF * 2);
  __hip_bfloat16* xgb = (__hip_bfloat16*)take((size_t)SLOTPAD * DMODEL * 2);
  __hip_bfloat16* hb  = (__hip_bfloat16*)take((size_t)SLOTPAD * HFF * 2);
  (void)ws_size; (void)in_sizes; (void)n_in; (void)out_size;

  hipMemsetAsync(ctrl, 0, 64 * sizeof(int), stream);
  hipMemsetAsync(out, 0, (size_t)TOK * DMODEL * 4, stream);
  transpose_cvt<<<dim3(HFF / 64, DMODEL / 64, NEXP), 256, 0, stream>>>(W1, W1t, DMODEL, HFF);
  transpose_cvt<<<dim3(DMODEL / 64, HFF / 64, NEXP), 256, 0, stream>>>(W2, W2t, HFF, DMODEL);
  router_kernel<<<TOK / 4, 256, 0, stream>>>(x, Wg, bg, idx, wtok, ctrl);
  scan_kernel<<<1, 64, 0, stream>>>(ctrl);
  scatter_kernel<<<TOK / 256, 256, 0, stream>>>(idx, wtok, ctrl, perm, wslot);
  gather_cvt_x<<<NASSIGN, 256, 0, stream>>>(x, perm, xgb);
  gemm1_kernel<<<MAXRT * (HFF / BN), 256, 0, stream>>>(xgb, W1t, b1, hb, ctrl);
  gemm2_kernel<<<MAXRT * (DMODEL / BN), 256, 0, stream>>>(hb, W2t, b2, wslot, perm, out, ctrl);
}